// Round 10
// baseline (185.100 us; speedup 1.0000x reference)
//
#include <hip/hip_runtime.h>
#include <stdint.h>

typedef __attribute__((ext_vector_type(4))) float f32x4;
typedef __attribute__((ext_vector_type(8))) short short8_t;     // 8 bf16 for MFMA operand
typedef __attribute__((ext_vector_type(8))) unsigned short ushort8_t;

__device__ __forceinline__ unsigned short f2bf(float f) {
    unsigned int u = __builtin_bit_cast(unsigned int, f);
    u = (u + 0x7fffu + ((u >> 16) & 1u)) >> 16;   // round-to-nearest-even
    return (unsigned short)u;
}
__device__ __forceinline__ float bf2f(unsigned short h) {
    unsigned int u = ((unsigned int)h) << 16;
    return __builtin_bit_cast(float, u);
}

// async global->LDS, 16B per lane. LDS dest = wave-uniform base + lane*16.
__device__ __forceinline__ void gll16(const unsigned short* g, unsigned short* l) {
    __builtin_amdgcn_global_load_lds(
        (const __attribute__((address_space(1))) void*)g,
        (__attribute__((address_space(3))) void*)l, 16, 0, 0);
}

// ---------------------------------------------------------------- prep weights
__global__ __launch_bounds__(256) void prep_w(
    const float* __restrict__ g_w, const float* __restrict__ W_w,
    const float* __restrict__ W_b, const float* __restrict__ gamma,
    const float* __restrict__ beta, const float* __restrict__ mean,
    const float* __restrict__ var,
    unsigned short* __restrict__ gwb, unsigned short* __restrict__ wwb,
    float* __restrict__ bnA, float* __restrict__ bnB)
{
    int i = blockIdx.x * 256 + threadIdx.x;
    if (i < 256 * 512) { gwb[i] = f2bf(g_w[i]); wwb[i] = f2bf(W_w[i]); }
    if (i < 512) {
        float is = rsqrtf(var[i] + 1e-5f);
        float a = gamma[i] * is;
        bnA[i] = a;
        bnB[i] = (W_b[i] - mean[i]) * a + beta[i];
    }
}

// ---------------- fused Q+K build: read x once, write Q^T bf16 and pooled K^T bf16
// Block: 32 channels x 128 positions (= 2 image rows).  grid (32, 16, 8), block 256.
__global__ __launch_bounds__(256) void build_qk(
    const float* __restrict__ x, unsigned short* __restrict__ Qh,
    unsigned short* __restrict__ Kh)
{
    __shared__ float t[32][129];   // +1 pad: conflict-free transposed reads
    int b = blockIdx.z;
    int p0 = blockIdx.x * 128, c0 = blockIdx.y * 32;
    const float* xb = x + (long)b * 512 * 4096;
    int tid = threadIdx.x;
    for (int i = 0; i < 16; i++) {
        int idx = i * 256 + tid;
        int c = idx >> 7, p = idx & 127;
        t[c][p] = xb[(long)(c0 + c) * 4096 + p0 + p];
    }
    __syncthreads();
    unsigned short* qb = Qh + (long)b * 4096 * 512;
    for (int i = 0; i < 16; i++) {
        int idx = i * 256 + tid;
        int p = idx >> 5, c = idx & 31;
        qb[(long)(p0 + p) * 512 + c0 + c] = f2bf(t[c][p]);
    }
    unsigned short* kb = Kh + (long)b * 1024 * 512;
    int kp0 = p0 >> 2;   // pooled row (p0/128)*32
    for (int i = 0; i < 4; i++) {
        int idx = i * 256 + tid;
        int w = idx >> 5, c = idx & 31;
        float v = fmaxf(fmaxf(t[c][2 * w], t[c][2 * w + 1]),
                        fmaxf(t[c][64 + 2 * w], t[c][64 + 2 * w + 1]));
        kb[(long)(kp0 + w) * 512 + c0 + c] = f2bf(v);
    }
}

// ---------------- V build: Gp[b][ci][k'] = bf16(g_b[ci] + maxpool2(Gt)[ci][k'])
// Gt is bf16 [b][p=4096][ci=256].  grid (1024/32, 256/8, 8), block 256
__global__ __launch_bounds__(256) void build_v(
    const unsigned short* __restrict__ Gt, const float* __restrict__ g_b,
    unsigned short* __restrict__ Gp)
{
    int b = blockIdx.z;
    int k  = blockIdx.x * 32 + (threadIdx.x & 31);
    int ci = blockIdx.y * 8 + (threadIdx.x >> 5);
    int h = k >> 5, w = k & 31;
    const unsigned short* g = Gt + (long)b * 4096 * 256;
    long p = (long)(h * 128 + w * 2) * 256 + ci;
    float v0 = bf2f(g[p]),        v1 = bf2f(g[p + 256]);
    float v2 = bf2f(g[p + 64*256]), v3 = bf2f(g[p + 65*256]);
    float v = fmaxf(fmaxf(v0, v1), fmaxf(v2, v3)) + g_b[ci];
    Gp[(long)b * 256 * 1024 + (long)ci * 1024 + k] = f2bf(v);
}

// ------------------------------------------- fused softmax + PV (deferred norm)
// Per block: 32 q-rows (occupancy: 1024 blocks, 4/CU), full 1024 keys, 256 ci.
// Pass 1: max-only scan of S (8 threads/row) -> lm.
// Pass 2: per 64-key block, p = exp(s-m) unnormalized -> bf16 -> MFMA;
// row sums accumulated alongside; 1/l applied in epilogue.
__global__ __launch_bounds__(256) void pv_fused(
    const unsigned short* __restrict__ S, long sbstr,
    const unsigned short* __restrict__ Gp, long gbstr,
    unsigned short* __restrict__ Y, long ybstr)
{
    __shared__ unsigned short lV[256 * 64];   // 32 KB
    __shared__ unsigned short lP[32 * 64];    // 4 KB
    __shared__ float pm[256];
    __shared__ float lm[32], li[32];

    const int tid = threadIdx.x;
    const int wid = tid >> 6, lane = tid & 63;

    // XCD-aware remap: each XCD owns one batch's q-blocks (S, V stay L2-local)
    unsigned gx = gridDim.x, gy = gridDim.y;
    unsigned nwg = gx * gy;
    unsigned lin = blockIdx.x + gx * blockIdx.y;
    unsigned l = ((nwg & 7u) == 0u) ? ((lin & 7u) * (nwg >> 3) + (lin >> 3)) : lin;
    unsigned bx = l % gx, by = l / gx;

    const int q0 = (int)bx * 32;
    const unsigned short* Sb = S + by * sbstr + (long)q0 * 1024;
    const unsigned short* Gb = Gp + by * gbstr;
    unsigned short* Yb = Y + by * ybstr + (long)q0 * 256;

    // ---- pass 1: per-row max over 1024 keys (8 threads/row, max-only)
    {
        int r = tid >> 3, qq = tid & 7;
        const unsigned short* p = Sb + (long)r * 1024 + qq * 128;
        float m = -3.0e38f;
        for (int i = 0; i < 16; i++) {
            ushort8_t v = *(const ushort8_t*)(p + i * 8);
            float c0 = fmaxf(bf2f(v[0]), bf2f(v[1]));
            float c1 = fmaxf(bf2f(v[2]), bf2f(v[3]));
            float c2 = fmaxf(bf2f(v[4]), bf2f(v[5]));
            float c3 = fmaxf(bf2f(v[6]), bf2f(v[7]));
            m = fmaxf(m, fmaxf(fmaxf(c0, c1), fmaxf(c2, c3)));
        }
        pm[tid] = m;
    }
    __syncthreads();
    if (tid < 32) {
        float m = pm[tid * 8];
        for (int j = 1; j < 8; j++) m = fmaxf(m, pm[tid * 8 + j]);
        lm[tid] = m;
    }

    const int wr = wid >> 1, wc = wid & 1;
    const int lr = lane & 15, lg = lane >> 4;
    const int srA = lane >> 3;
    const int scg = (((lane & 7) ^ srA) << 3);
    const int pr = tid >> 3;            // lP row 0..31
    const int pc = tid & 7;             // one 8-key chunk

    f32x4 acc[8];
    for (int ni = 0; ni < 8; ni++) acc[ni] = (f32x4){0.f, 0.f, 0.f, 0.f};
    float psum = 0.f;                   // this thread's 1/8-row sum of p

    for (int kb = 0; kb < 16; kb++) {
        __syncthreads();   // prev MFMA reads done; lm visible at kb=0
        // stage V tile [256 ci][64 keys] (linear LDS dest, pre-swizzled source)
        for (int i = 0; i < 8; i++) {
            int cibase = i * 32 + wid * 8;
            gll16(Gb + (long)(cibase + srA) * 1024 + kb * 64 + scg, &lV[cibase * 64]);
        }
        // P chunk: p = exp(s - m) -> bf16 -> lP (XOR chunk swizzle); overlaps DMA
        {
            float m = lm[pr];
            const unsigned short* sp = Sb + (long)pr * 1024 + kb * 64 + pc * 8;
            ushort8_t v = *(const ushort8_t*)sp;
            ushort8_t o8;
            for (int e = 0; e < 8; e++) {
                float pe = __expf(bf2f(v[e]) - m);
                psum += pe;
                o8[e] = f2bf(pe);
            }
            *(ushort8_t*)(&lP[pr * 64 + ((pc ^ (pr & 7)) * 8)]) = o8;
        }
        __syncthreads();   // drains vmcnt(0) + LDS writes
        for (int ks = 0; ks < 2; ks++) {
            short8_t af;
            {
                int row = wr * 16 + lr;
                int ch = ((ks * 4 + lg) ^ (row & 7)) * 8;
                af = *(const short8_t*)(&lP[row * 64 + ch]);
            }
            for (int ni = 0; ni < 8; ni++) {
                int row = wc * 128 + ni * 16 + lr;
                int ch = ((ks * 4 + lg) ^ (row & 7)) * 8;
                short8_t bfr = *(const short8_t*)(&lV[row * 64 + ch]);
                acc[ni] = __builtin_amdgcn_mfma_f32_16x16x32_bf16(
                    af, bfr, acc[ni], 0, 0, 0);
            }
        }
    }

    // reduce 8 partial sums per row -> li
    psum += __shfl_xor(psum, 1);
    psum += __shfl_xor(psum, 2);
    psum += __shfl_xor(psum, 4);
    if ((tid & 7) == 0) li[pr] = 1.0f / psum;
    __syncthreads();

    // epilogue: Y[row][ci] = bf16(acc * 1/l)
    for (int ni = 0; ni < 8; ni++) {
        int ci = wc * 128 + ni * 16 + lr;
        int rbase = wr * 16 + lg * 4;
        for (int r = 0; r < 4; r++) {
            int row = rbase + r;
            Yb[(long)row * 256 + ci] = f2bf(acc[ni][r] * li[row]);
        }
    }
}

// -------------------------------------------------------------------- GEMM
// C[m][n] = sum_k A[m][k]*B[n][k].  128x128 tile, BK=64, 4 waves 2x2.
// global_load_lds staging (linear LDS dest, XOR-swizzled source; read same XOR).
// XCD block remap when nwg%8==0.
// EPI: 0 f32 store, 1 bf16 store, 2 v*bnA[m]+bnB[m]+Xres f32 store.
template<int EPI>
__global__ __launch_bounds__(256) void gemm_abt(
    const unsigned short* __restrict__ A, int lda, long abstr,
    const unsigned short* __restrict__ B, int ldb, long bbstr,
    void* __restrict__ Cv, int ldc, long cbstr,
    int K,
    const float* __restrict__ bnA, const float* __restrict__ bnB,
    const float* __restrict__ Xres, long xbstr)
{
    __shared__ unsigned short lA[128 * 64];
    __shared__ unsigned short lB[128 * 64];
    const int tid = threadIdx.x;
    const int wid = tid >> 6, lane = tid & 63;

    // ---- XCD-aware block remap (bijective; identity if nwg%8 != 0)
    unsigned gx = gridDim.x, gy = gridDim.y;
    unsigned nwg = gx * gy * gridDim.z;
    unsigned lin = blockIdx.x + gx * (blockIdx.y + gy * blockIdx.z);
    unsigned l = ((nwg & 7u) == 0u) ? ((lin & 7u) * (nwg >> 3) + (lin >> 3)) : lin;
    unsigned bx = l % gx;
    unsigned rem = l / gx;
    unsigned by = rem % gy;
    unsigned bz = rem / gy;

    const int z = (int)bz;
    const int m0 = (int)by * 128, n0 = (int)bx * 128;
    const unsigned short* Ab = A + z * abstr;
    const unsigned short* Bb = B + z * bbstr;
    const int wr = wid >> 1, wc = wid & 1;
    const int lr = lane & 15, lg = lane >> 4;

    const int srA = lane >> 3;                         // 0..7
    const int scg = (((lane & 7) ^ srA) << 3);         // element offset 0..56

    f32x4 acc[4][4];
    for (int mi = 0; mi < 4; mi++)
        for (int ni = 0; ni < 4; ni++)
            acc[mi][ni] = (f32x4){0.f, 0.f, 0.f, 0.f};

    for (int k0 = 0; k0 < K; k0 += 64) {
        __syncthreads();   // previous iter's LDS reads complete
        for (int i = 0; i < 4; i++) {
            int rowbase = i * 32 + wid * 8;
            gll16(Ab + (long)(m0 + rowbase + srA) * lda + k0 + scg, &lA[rowbase * 64]);
            gll16(Bb + (long)(n0 + rowbase + srA) * ldb + k0 + scg, &lB[rowbase * 64]);
        }
        __syncthreads();   // drains vmcnt(0): tiles resident
        for (int kk = 0; kk < 2; kk++) {
            short8_t af[4], bfr[4];
            for (int mi = 0; mi < 4; mi++) {
                int row = wr * 64 + mi * 16 + lr;
                int ch = ((kk * 4 + lg) ^ (row & 7)) * 8;
                af[mi] = *(const short8_t*)(&lA[row * 64 + ch]);
            }
            for (int ni = 0; ni < 4; ni++) {
                int row = wc * 64 + ni * 16 + lr;
                int ch = ((kk * 4 + lg) ^ (row & 7)) * 8;
                bfr[ni] = *(const short8_t*)(&lB[row * 64 + ch]);
            }
            for (int mi = 0; mi < 4; mi++)
                for (int ni = 0; ni < 4; ni++)
                    acc[mi][ni] = __builtin_amdgcn_mfma_f32_16x16x32_bf16(
                        af[mi], bfr[ni], acc[mi][ni], 0, 0, 0);
        }
    }

    // epilogue: lane holds D[row=(lane>>4)*4+r][col=lane&15]
    for (int mi = 0; mi < 4; mi++) {
        for (int ni = 0; ni < 4; ni++) {
            int ncol = n0 + wc * 64 + ni * 16 + lr;
            int mrow = m0 + wr * 64 + mi * 16 + lg * 4;
            for (int r = 0; r < 4; r++) {
                int row = mrow + r;
                float v = acc[mi][ni][r];
                long idx = z * cbstr + (long)row * ldc + ncol;
                if (EPI == 0) {
                    ((float*)Cv)[idx] = v;
                } else if (EPI == 1) {
                    ((unsigned short*)Cv)[idx] = f2bf(v);
                } else {
                    float o = v * bnA[row] + bnB[row] + Xres[z * xbstr + (long)row * ldc + ncol];
                    ((float*)Cv)[idx] = o;
                }
            }
        }
    }
}

// fallback if workspace too small (diagnostic: out = x)
__global__ void copy_residual(const float* __restrict__ x, float* __restrict__ out, long n)
{
    for (long i = blockIdx.x * 256ll + threadIdx.x; i < n; i += (long)gridDim.x * 256)
        out[i] = x[i];
}

extern "C" void kernel_launch(void* const* d_in, const int* in_sizes, int n_in,
                              void* d_out, int out_size, void* d_ws, size_t ws_size,
                              hipStream_t stream)
{
    const float* x     = (const float*)d_in[0];
    const float* g_w   = (const float*)d_in[1];
    const float* g_b   = (const float*)d_in[2];
    const float* W_w   = (const float*)d_in[3];
    const float* W_b   = (const float*)d_in[4];
    const float* gamma = (const float*)d_in[5];
    const float* beta  = (const float*)d_in[6];
    const float* mean  = (const float*)d_in[7];
    const float* var   = (const float*)d_in[8];
    float* out = (float*)d_out;

    char* ws = (char*)d_ws;
    size_t o = 0;
    auto alloc = [&](size_t bytes) { size_t r = o; o = (o + bytes + 255) & ~(size_t)255; return r; };
    size_t o_gwb = alloc(256 * 512 * 2);
    size_t o_wwb = alloc(512 * 256 * 2);
    size_t o_bnA = alloc(512 * 4);
    size_t o_bnB = alloc(512 * 4);
    size_t o_q   = alloc(8ull * 4096 * 512 * 2);   // Qh bf16
    size_t o_k   = alloc(8ull * 1024 * 512 * 2);   // Kh bf16
    size_t o_gp  = alloc(8ull * 256 * 1024 * 2);   // V^T (pooled g, bf16)
    size_t o_y   = alloc(8ull * 4096 * 256 * 2);   // Y (also holds Gt before pooling)
    size_t o_s   = o;                               // S bf16 logits
    const size_t srow_bytes = 1024ull * 2;          // one S row (bf16)
    const size_t sb1 = 4096ull * srow_bytes;        // one batch of S (8 MB)

    // Plan: G = batches of S at once (z-grouped); else RC = row-chunk within a batch.
    int G = 0, RC = 0;
    if      (o_s + 8 * sb1 <= ws_size) G = 8;
    else if (o_s + 4 * sb1 <= ws_size) G = 4;
    else if (o_s + 2 * sb1 <= ws_size) G = 2;
    else if (o_s + 1 * sb1 <= ws_size) G = 1;
    else {
        for (int rc = 2048; rc >= 128; rc >>= 1)
            if (o_s + (size_t)rc * srow_bytes <= ws_size) { RC = rc; break; }
        if (!RC) {  // ws too small — diagnostic fallback
            copy_residual<<<dim3(2048), dim3(256), 0, stream>>>(x, out, (long)out_size);
            return;
        }
    }

    unsigned short* gwb = (unsigned short*)(ws + o_gwb);
    unsigned short* wwb = (unsigned short*)(ws + o_wwb);
    float* bnA = (float*)(ws + o_bnA);
    float* bnB = (float*)(ws + o_bnB);
    unsigned short* Qh  = (unsigned short*)(ws + o_q);
    unsigned short* Kh  = (unsigned short*)(ws + o_k);
    unsigned short* Gp  = (unsigned short*)(ws + o_gp);
    unsigned short* Y   = (unsigned short*)(ws + o_y);
    unsigned short* S   = (unsigned short*)(ws + o_s);

    prep_w<<<dim3(512), dim3(256), 0, stream>>>(g_w, W_w, W_b, gamma, beta, mean, var,
                                                gwb, wwb, bnA, bnB);
    build_qk<<<dim3(32, 16, 8), dim3(256), 0, stream>>>(x, Qh, Kh);

    // G-conv: Gt[b][p][ci] (bf16, into Y slot) = Qh · gwb^T   (M=4096,N=256,K=512)
    gemm_abt<1><<<dim3(2, 32, 8), dim3(256), 0, stream>>>(
        Qh, 512, 4096l * 512,
        gwb, 512, 0,
        (void*)Y, 256, 4096l * 256, 512,
        nullptr, nullptr, nullptr, 0);

    build_v<<<dim3(32, 32, 8), dim3(256), 0, stream>>>(Y, g_b, Gp);

    if (G) {
        for (int bg = 0; bg < 8; bg += G) {
            // QK^T: bf16 in, bf16 logits out (K=512)
            gemm_abt<1><<<dim3(8, 32, G), dim3(256), 0, stream>>>(
                Qh + (size_t)bg * 4096 * 512, 512, 4096l * 512,
                Kh + (size_t)bg * 1024 * 512, 512, 1024l * 512,
                (void*)S, 1024, 4096l * 1024, 512,
                nullptr, nullptr, nullptr, 0);
            // fused softmax + PV (max pre-pass + deferred normalization), 32-row blocks
            pv_fused<<<dim3(128, G), dim3(256), 0, stream>>>(
                S, 4096l * 1024,
                Gp + (size_t)bg * 256 * 1024, 256l * 1024,
                Y + (size_t)bg * 4096 * 256, 4096l * 256);
        }
    } else {
        // Row-chunked path (small workspace): S holds RC rows at a time.
        for (int b = 0; b < 8; b++) {
            for (int r0 = 0; r0 < 4096; r0 += RC) {
                const unsigned short* Aq = Qh + (size_t)b * 4096 * 512 + (size_t)r0 * 512;
                gemm_abt<1><<<dim3(8, RC / 128, 1), dim3(256), 0, stream>>>(
                    Aq, 512, 0,
                    Kh + (size_t)b * 1024 * 512, 512, 0,
                    (void*)S, 1024, 0, 512,
                    nullptr, nullptr, nullptr, 0);
                pv_fused<<<dim3(RC / 32, 1), dim3(256), 0, stream>>>(
                    S, 0,
                    Gp + (size_t)b * 256 * 1024, 0,
                    Y + ((size_t)b * 4096 + r0) * 256, 0);
            }
        }
    }

    // W-conv + BN + residual: out[b][o][p] = (wwb·Y^T)*bnA[o]+bnB[o]+x  (M=512,N=4096,K=256)
    gemm_abt<2><<<dim3(32, 4, 8), dim3(256), 0, stream>>>(
        wwb, 256, 0,
        Y, 256, 4096l * 256,
        (void*)out, 4096, 512l * 4096, 256,
        bnA, bnB, x, 512l * 4096);
}

// Round 11
// 178.546 us; speedup vs baseline: 1.0367x; 1.0367x over previous
//
#include <hip/hip_runtime.h>
#include <stdint.h>

typedef __attribute__((ext_vector_type(4))) float f32x4;
typedef __attribute__((ext_vector_type(8))) short short8_t;     // 8 bf16 for MFMA operand
typedef __attribute__((ext_vector_type(8))) unsigned short ushort8_t;

__device__ __forceinline__ unsigned short f2bf(float f) {
    unsigned int u = __builtin_bit_cast(unsigned int, f);
    u = (u + 0x7fffu + ((u >> 16) & 1u)) >> 16;   // round-to-nearest-even
    return (unsigned short)u;
}
__device__ __forceinline__ float bf2f(unsigned short h) {
    unsigned int u = ((unsigned int)h) << 16;
    return __builtin_bit_cast(float, u);
}

// async global->LDS, 16B per lane. LDS dest = wave-uniform base + lane*16.
__device__ __forceinline__ void gll16(const unsigned short* g, unsigned short* l) {
    __builtin_amdgcn_global_load_lds(
        (const __attribute__((address_space(1))) void*)g,
        (__attribute__((address_space(3))) void*)l, 16, 0, 0);
}

// ---------------------------------------------------------------- prep weights
__global__ __launch_bounds__(256) void prep_w(
    const float* __restrict__ g_w, const float* __restrict__ W_w,
    const float* __restrict__ W_b, const float* __restrict__ gamma,
    const float* __restrict__ beta, const float* __restrict__ mean,
    const float* __restrict__ var,
    unsigned short* __restrict__ gwb, unsigned short* __restrict__ wwb,
    float* __restrict__ bnA, float* __restrict__ bnB)
{
    int i = blockIdx.x * 256 + threadIdx.x;
    if (i < 256 * 512) { gwb[i] = f2bf(g_w[i]); wwb[i] = f2bf(W_w[i]); }
    if (i < 512) {
        float is = rsqrtf(var[i] + 1e-5f);
        float a = gamma[i] * is;
        bnA[i] = a;
        bnB[i] = (W_b[i] - mean[i]) * a + beta[i];
    }
}

// ---------------- fused Q+K build: read x once, write Q^T bf16 and pooled K^T bf16
// Block: 32 channels x 128 positions (= 2 image rows).  grid (32, 16, 8), block 256.
__global__ __launch_bounds__(256) void build_qk(
    const float* __restrict__ x, unsigned short* __restrict__ Qh,
    unsigned short* __restrict__ Kh)
{
    __shared__ float t[32][129];   // +1 pad: conflict-free transposed reads
    int b = blockIdx.z;
    int p0 = blockIdx.x * 128, c0 = blockIdx.y * 32;
    const float* xb = x + (long)b * 512 * 4096;
    int tid = threadIdx.x;
    for (int i = 0; i < 16; i++) {
        int idx = i * 256 + tid;
        int c = idx >> 7, p = idx & 127;
        t[c][p] = xb[(long)(c0 + c) * 4096 + p0 + p];
    }
    __syncthreads();
    unsigned short* qb = Qh + (long)b * 4096 * 512;
    for (int i = 0; i < 16; i++) {
        int idx = i * 256 + tid;
        int p = idx >> 5, c = idx & 31;
        qb[(long)(p0 + p) * 512 + c0 + c] = f2bf(t[c][p]);
    }
    unsigned short* kb = Kh + (long)b * 1024 * 512;
    int kp0 = p0 >> 2;   // pooled row (p0/128)*32
    for (int i = 0; i < 4; i++) {
        int idx = i * 256 + tid;
        int w = idx >> 5, c = idx & 31;
        float v = fmaxf(fmaxf(t[c][2 * w], t[c][2 * w + 1]),
                        fmaxf(t[c][64 + 2 * w], t[c][64 + 2 * w + 1]));
        kb[(long)(kp0 + w) * 512 + c0 + c] = f2bf(v);
    }
}

// ---------------- V build: Gp[b][ci][k'] = bf16(g_b[ci] + maxpool2(Gt)[ci][k'])
// Gt is bf16 [b][p=4096][ci=256].  grid (1024/32, 256/8, 8), block 256
__global__ __launch_bounds__(256) void build_v(
    const unsigned short* __restrict__ Gt, const float* __restrict__ g_b,
    unsigned short* __restrict__ Gp)
{
    int b = blockIdx.z;
    int k  = blockIdx.x * 32 + (threadIdx.x & 31);
    int ci = blockIdx.y * 8 + (threadIdx.x >> 5);
    int h = k >> 5, w = k & 31;
    const unsigned short* g = Gt + (long)b * 4096 * 256;
    long p = (long)(h * 128 + w * 2) * 256 + ci;
    float v0 = bf2f(g[p]),        v1 = bf2f(g[p + 256]);
    float v2 = bf2f(g[p + 64*256]), v3 = bf2f(g[p + 65*256]);
    float v = fmaxf(fmaxf(v0, v1), fmaxf(v2, v3)) + g_b[ci];
    Gp[(long)b * 256 * 1024 + (long)ci * 1024 + k] = f2bf(v);
}

// ---------------- streaming row max: one wave per 1024-elem row, coalesced.
// rows indexed locally from S base; Smax[row] = max of row.  grid rows/4, block 256.
__global__ __launch_bounds__(256) void smax_rows(
    const unsigned short* __restrict__ S, float* __restrict__ Smax)
{
    long row = (long)blockIdx.x * 4 + (threadIdx.x >> 6);
    int lane = threadIdx.x & 63;
    const unsigned short* r = S + row * 1024 + lane * 16;
    ushort8_t v0 = *(const ushort8_t*)r;
    ushort8_t v1 = *(const ushort8_t*)(r + 8);
    float m = -3.0e38f;
    for (int e = 0; e < 8; e++) m = fmaxf(m, fmaxf(bf2f(v0[e]), bf2f(v1[e])));
    for (int off = 32; off; off >>= 1) m = fmaxf(m, __shfl_xor(m, off));
    if (lane == 0) Smax[row] = m;
}

// ------------------------------------------- fused softmax + PV (deferred norm)
// Per block: 64 q-rows, full 1024 keys, 256 ci.  No pass-1: row max comes from
// Smax (exact f32 max of the bf16 logits).  p = exp(s-m) unnormalized -> bf16 ->
// MFMA; row sums accumulated alongside; 1/l applied in epilogue.
__global__ __launch_bounds__(256) void pv_fused(
    const unsigned short* __restrict__ S, long sbstr,
    const float* __restrict__ Smax, long mxstr,
    const unsigned short* __restrict__ Gp, long gbstr,
    unsigned short* __restrict__ Y, long ybstr)
{
    __shared__ unsigned short lV[256 * 64];   // 32 KB
    __shared__ unsigned short lP[64 * 64];    // 8 KB
    __shared__ float li[64];

    const int tid = threadIdx.x;
    const int wid = tid >> 6, lane = tid & 63;

    // XCD-aware remap: each XCD owns one batch's q-blocks (S, V stay L2-local)
    unsigned gx = gridDim.x, gy = gridDim.y;
    unsigned nwg = gx * gy;
    unsigned lin = blockIdx.x + gx * blockIdx.y;
    unsigned l = ((nwg & 7u) == 0u) ? ((lin & 7u) * (nwg >> 3) + (lin >> 3)) : lin;
    unsigned bx = l % gx, by = l / gx;

    const int q0 = (int)bx * 64;
    const unsigned short* Sb = S + by * sbstr + (long)q0 * 1024;
    const unsigned short* Gb = Gp + by * gbstr;
    unsigned short* Yb = Y + by * ybstr + (long)q0 * 256;

    const int wr = wid >> 1, wc = wid & 1;
    const int lr = lane & 15, lg = lane >> 4;
    const int srA = lane >> 3;
    const int scg = (((lane & 7) ^ srA) << 3);
    const int pr = tid >> 2;            // lP row 0..63
    const int pc = (tid & 3) * 2;       // chunk base (2 chunks of 8 keys)

    const float m = Smax[by * mxstr + q0 + pr];   // exact row max (f32)

    f32x4 acc[2][8];
    for (int mi = 0; mi < 2; mi++)
        for (int ni = 0; ni < 8; ni++)
            acc[mi][ni] = (f32x4){0.f, 0.f, 0.f, 0.f};
    float psum = 0.f;                   // this thread's quarter-row sum of p

    for (int kb = 0; kb < 16; kb++) {
        __syncthreads();   // prev MFMA reads done
        // stage V tile [256 ci][64 keys] (linear LDS dest, pre-swizzled source)
        for (int i = 0; i < 8; i++) {
            int cibase = i * 32 + wid * 8;
            gll16(Gb + (long)(cibase + srA) * 1024 + kb * 64 + scg, &lV[cibase * 64]);
        }
        // P chunk: p = exp(s - m) -> bf16 -> lP (XOR chunk swizzle); overlaps DMA
        {
            const unsigned short* sp = Sb + (long)pr * 1024 + kb * 64 + pc * 8;
            for (int j = 0; j < 2; j++) {
                ushort8_t v = *(const ushort8_t*)(sp + j * 8);
                ushort8_t o8;
                for (int e = 0; e < 8; e++) {
                    float pe = __expf(bf2f(v[e]) - m);
                    psum += pe;
                    o8[e] = f2bf(pe);
                }
                int c = pc + j;
                *(ushort8_t*)(&lP[pr * 64 + ((c ^ (pr & 7)) * 8)]) = o8;
            }
        }
        __syncthreads();   // drains vmcnt(0) + LDS writes
        for (int ks = 0; ks < 2; ks++) {
            short8_t af[2], bfr[8];
            for (int mi = 0; mi < 2; mi++) {
                int row = wr * 32 + mi * 16 + lr;
                int ch = ((ks * 4 + lg) ^ (row & 7)) * 8;
                af[mi] = *(const short8_t*)(&lP[row * 64 + ch]);
            }
            for (int ni = 0; ni < 8; ni++) {
                int row = wc * 128 + ni * 16 + lr;
                int ch = ((ks * 4 + lg) ^ (row & 7)) * 8;
                bfr[ni] = *(const short8_t*)(&lV[row * 64 + ch]);
            }
            for (int mi = 0; mi < 2; mi++)
                for (int ni = 0; ni < 8; ni++)
                    acc[mi][ni] = __builtin_amdgcn_mfma_f32_16x16x32_bf16(
                        af[mi], bfr[ni], acc[mi][ni], 0, 0, 0);
        }
    }

    // reduce 4 partial sums per row -> li
    psum += __shfl_xor(psum, 1);
    psum += __shfl_xor(psum, 2);
    if ((tid & 3) == 0) li[pr] = 1.0f / psum;
    __syncthreads();

    // epilogue: Y[row][ci] = bf16(acc * 1/l)
    for (int mi = 0; mi < 2; mi++) {
        for (int ni = 0; ni < 8; ni++) {
            int ci = wc * 128 + ni * 16 + lr;
            int rbase = wr * 32 + mi * 16 + lg * 4;
            for (int r = 0; r < 4; r++) {
                int row = rbase + r;
                Yb[(long)row * 256 + ci] = f2bf(acc[mi][ni][r] * li[row]);
            }
        }
    }
}

// -------------------------------------------------------------------- GEMM
// C[m][n] = sum_k A[m][k]*B[n][k].  128x128 tile, BK=64, 4 waves 2x2.
// global_load_lds staging (linear LDS dest, XOR-swizzled source; read same XOR).
// XCD block remap when nwg%8==0.
// EPI: 0 f32 store, 1 bf16 store, 2 v*bnA[m]+bnB[m]+Xres f32 store.
template<int EPI>
__global__ __launch_bounds__(256) void gemm_abt(
    const unsigned short* __restrict__ A, int lda, long abstr,
    const unsigned short* __restrict__ B, int ldb, long bbstr,
    void* __restrict__ Cv, int ldc, long cbstr,
    int K,
    const float* __restrict__ bnA, const float* __restrict__ bnB,
    const float* __restrict__ Xres, long xbstr)
{
    __shared__ unsigned short lA[128 * 64];
    __shared__ unsigned short lB[128 * 64];
    const int tid = threadIdx.x;
    const int wid = tid >> 6, lane = tid & 63;

    // ---- XCD-aware block remap (bijective; identity if nwg%8 != 0)
    unsigned gx = gridDim.x, gy = gridDim.y;
    unsigned nwg = gx * gy * gridDim.z;
    unsigned lin = blockIdx.x + gx * (blockIdx.y + gy * blockIdx.z);
    unsigned l = ((nwg & 7u) == 0u) ? ((lin & 7u) * (nwg >> 3) + (lin >> 3)) : lin;
    unsigned bx = l % gx;
    unsigned rem = l / gx;
    unsigned by = rem % gy;
    unsigned bz = rem / gy;

    const int z = (int)bz;
    const int m0 = (int)by * 128, n0 = (int)bx * 128;
    const unsigned short* Ab = A + z * abstr;
    const unsigned short* Bb = B + z * bbstr;
    const int wr = wid >> 1, wc = wid & 1;
    const int lr = lane & 15, lg = lane >> 4;

    const int srA = lane >> 3;                         // 0..7
    const int scg = (((lane & 7) ^ srA) << 3);         // element offset 0..56

    f32x4 acc[4][4];
    for (int mi = 0; mi < 4; mi++)
        for (int ni = 0; ni < 4; ni++)
            acc[mi][ni] = (f32x4){0.f, 0.f, 0.f, 0.f};

    for (int k0 = 0; k0 < K; k0 += 64) {
        __syncthreads();   // previous iter's LDS reads complete
        for (int i = 0; i < 4; i++) {
            int rowbase = i * 32 + wid * 8;
            gll16(Ab + (long)(m0 + rowbase + srA) * lda + k0 + scg, &lA[rowbase * 64]);
            gll16(Bb + (long)(n0 + rowbase + srA) * ldb + k0 + scg, &lB[rowbase * 64]);
        }
        __syncthreads();   // drains vmcnt(0): tiles resident
        for (int kk = 0; kk < 2; kk++) {
            short8_t af[4], bfr[4];
            for (int mi = 0; mi < 4; mi++) {
                int row = wr * 64 + mi * 16 + lr;
                int ch = ((kk * 4 + lg) ^ (row & 7)) * 8;
                af[mi] = *(const short8_t*)(&lA[row * 64 + ch]);
            }
            for (int ni = 0; ni < 4; ni++) {
                int row = wc * 64 + ni * 16 + lr;
                int ch = ((kk * 4 + lg) ^ (row & 7)) * 8;
                bfr[ni] = *(const short8_t*)(&lB[row * 64 + ch]);
            }
            for (int mi = 0; mi < 4; mi++)
                for (int ni = 0; ni < 4; ni++)
                    acc[mi][ni] = __builtin_amdgcn_mfma_f32_16x16x32_bf16(
                        af[mi], bfr[ni], acc[mi][ni], 0, 0, 0);
        }
    }

    // epilogue: lane holds D[row=(lane>>4)*4+r][col=lane&15]
    for (int mi = 0; mi < 4; mi++) {
        for (int ni = 0; ni < 4; ni++) {
            int ncol = n0 + wc * 64 + ni * 16 + lr;
            int mrow = m0 + wr * 64 + mi * 16 + lg * 4;
            for (int r = 0; r < 4; r++) {
                int row = mrow + r;
                float v = acc[mi][ni][r];
                long idx = z * cbstr + (long)row * ldc + ncol;
                if (EPI == 0) {
                    ((float*)Cv)[idx] = v;
                } else if (EPI == 1) {
                    ((unsigned short*)Cv)[idx] = f2bf(v);
                } else {
                    float o = v * bnA[row] + bnB[row] + Xres[z * xbstr + (long)row * ldc + ncol];
                    ((float*)Cv)[idx] = o;
                }
            }
        }
    }
}

// fallback if workspace too small (diagnostic: out = x)
__global__ void copy_residual(const float* __restrict__ x, float* __restrict__ out, long n)
{
    for (long i = blockIdx.x * 256ll + threadIdx.x; i < n; i += (long)gridDim.x * 256)
        out[i] = x[i];
}

extern "C" void kernel_launch(void* const* d_in, const int* in_sizes, int n_in,
                              void* d_out, int out_size, void* d_ws, size_t ws_size,
                              hipStream_t stream)
{
    const float* x     = (const float*)d_in[0];
    const float* g_w   = (const float*)d_in[1];
    const float* g_b   = (const float*)d_in[2];
    const float* W_w   = (const float*)d_in[3];
    const float* W_b   = (const float*)d_in[4];
    const float* gamma = (const float*)d_in[5];
    const float* beta  = (const float*)d_in[6];
    const float* mean  = (const float*)d_in[7];
    const float* var   = (const float*)d_in[8];
    float* out = (float*)d_out;

    char* ws = (char*)d_ws;
    size_t o = 0;
    auto alloc = [&](size_t bytes) { size_t r = o; o = (o + bytes + 255) & ~(size_t)255; return r; };
    size_t o_gwb = alloc(256 * 512 * 2);
    size_t o_wwb = alloc(512 * 256 * 2);
    size_t o_bnA = alloc(512 * 4);
    size_t o_bnB = alloc(512 * 4);
    size_t o_q   = alloc(8ull * 4096 * 512 * 2);   // Qh bf16
    size_t o_k   = alloc(8ull * 1024 * 512 * 2);   // Kh bf16
    size_t o_gp  = alloc(8ull * 256 * 1024 * 2);   // V^T (pooled g, bf16)
    size_t o_y   = alloc(8ull * 4096 * 256 * 2);   // Y (also holds Gt before pooling)
    size_t o_m   = alloc(8ull * 4096 * 4);         // Smax f32 (exact row max)
    size_t o_s   = o;                               // S bf16 logits
    const size_t srow_bytes = 1024ull * 2;          // one S row (bf16)
    const size_t sb1 = 4096ull * srow_bytes;        // one batch of S (8 MB)

    // Plan: G = batches of S at once (z-grouped); else RC = row-chunk within a batch.
    int G = 0, RC = 0;
    if      (o_s + 8 * sb1 <= ws_size) G = 8;
    else if (o_s + 4 * sb1 <= ws_size) G = 4;
    else if (o_s + 2 * sb1 <= ws_size) G = 2;
    else if (o_s + 1 * sb1 <= ws_size) G = 1;
    else {
        for (int rc = 2048; rc >= 128; rc >>= 1)
            if (o_s + (size_t)rc * srow_bytes <= ws_size) { RC = rc; break; }
        if (!RC) {  // ws too small — diagnostic fallback
            copy_residual<<<dim3(2048), dim3(256), 0, stream>>>(x, out, (long)out_size);
            return;
        }
    }

    unsigned short* gwb = (unsigned short*)(ws + o_gwb);
    unsigned short* wwb = (unsigned short*)(ws + o_wwb);
    float* bnA = (float*)(ws + o_bnA);
    float* bnB = (float*)(ws + o_bnB);
    unsigned short* Qh  = (unsigned short*)(ws + o_q);
    unsigned short* Kh  = (unsigned short*)(ws + o_k);
    unsigned short* Gp  = (unsigned short*)(ws + o_gp);
    unsigned short* Y   = (unsigned short*)(ws + o_y);
    float* Smax         = (float*)(ws + o_m);
    unsigned short* S   = (unsigned short*)(ws + o_s);

    prep_w<<<dim3(512), dim3(256), 0, stream>>>(g_w, W_w, W_b, gamma, beta, mean, var,
                                                gwb, wwb, bnA, bnB);
    build_qk<<<dim3(32, 16, 8), dim3(256), 0, stream>>>(x, Qh, Kh);

    // G-conv: Gt[b][p][ci] (bf16, into Y slot) = Qh · gwb^T   (M=4096,N=256,K=512)
    gemm_abt<1><<<dim3(2, 32, 8), dim3(256), 0, stream>>>(
        Qh, 512, 4096l * 512,
        gwb, 512, 0,
        (void*)Y, 256, 4096l * 256, 512,
        nullptr, nullptr, nullptr, 0);

    build_v<<<dim3(32, 32, 8), dim3(256), 0, stream>>>(Y, g_b, Gp);

    if (G) {
        for (int bg = 0; bg < 8; bg += G) {
            // QK^T: bf16 in, bf16 logits out (K=512)
            gemm_abt<1><<<dim3(8, 32, G), dim3(256), 0, stream>>>(
                Qh + (size_t)bg * 4096 * 512, 512, 4096l * 512,
                Kh + (size_t)bg * 1024 * 512, 512, 1024l * 512,
                (void*)S, 1024, 4096l * 1024, 512,
                nullptr, nullptr, nullptr, 0);
            // streaming exact row max (one wave per row)
            smax_rows<<<dim3(G * 1024), dim3(256), 0, stream>>>(S, Smax);
            // fused softmax + PV (no pass-1; deferred normalization)
            pv_fused<<<dim3(64, G), dim3(256), 0, stream>>>(
                S, 4096l * 1024,
                Smax, 4096,
                Gp + (size_t)bg * 256 * 1024, 256l * 1024,
                Y + (size_t)bg * 4096 * 256, 4096l * 256);
        }
    } else {
        // Row-chunked path (small workspace): S holds RC rows at a time.
        for (int b = 0; b < 8; b++) {
            for (int r0 = 0; r0 < 4096; r0 += RC) {
                const unsigned short* Aq = Qh + (size_t)b * 4096 * 512 + (size_t)r0 * 512;
                gemm_abt<1><<<dim3(8, RC / 128, 1), dim3(256), 0, stream>>>(
                    Aq, 512, 0,
                    Kh + (size_t)b * 1024 * 512, 512, 0,
                    (void*)S, 1024, 0, 512,
                    nullptr, nullptr, nullptr, 0);
                smax_rows<<<dim3(RC / 4), dim3(256), 0, stream>>>(S, Smax);
                pv_fused<<<dim3(RC / 64, 1), dim3(256), 0, stream>>>(
                    S, 0,
                    Smax, 0,
                    Gp + (size_t)b * 256 * 1024, 0,
                    Y + ((size_t)b * 4096 + r0) * 256, 0);
            }
        }
    }

    // W-conv + BN + residual: out[b][o][p] = (wwb·Y^T)*bnA[o]+bnB[o]+x  (M=512,N=4096,K=256)
    gemm_abt<2><<<dim3(32, 4, 8), dim3(256), 0, stream>>>(
        wwb, 256, 0,
        Y, 256, 4096l * 256,
        (void*)out, 4096, 512l * 4096, 256,
        bnA, bnB, x, 512l * 4096);
}

// Round 12
// 174.604 us; speedup vs baseline: 1.0601x; 1.0226x over previous
//
#include <hip/hip_runtime.h>
#include <stdint.h>

typedef __attribute__((ext_vector_type(4))) float f32x4;
typedef __attribute__((ext_vector_type(8))) short short8_t;     // 8 bf16 for MFMA operand
typedef __attribute__((ext_vector_type(8))) unsigned short ushort8_t;

__device__ __forceinline__ unsigned short f2bf(float f) {
    unsigned int u = __builtin_bit_cast(unsigned int, f);
    u = (u + 0x7fffu + ((u >> 16) & 1u)) >> 16;   // round-to-nearest-even
    return (unsigned short)u;
}
__device__ __forceinline__ float bf2f(unsigned short h) {
    unsigned int u = ((unsigned int)h) << 16;
    return __builtin_bit_cast(float, u);
}

// async global->LDS, 16B per lane. LDS dest = wave-uniform base + lane*16.
__device__ __forceinline__ void gll16(const unsigned short* g, unsigned short* l) {
    __builtin_amdgcn_global_load_lds(
        (const __attribute__((address_space(1))) void*)g,
        (__attribute__((address_space(3))) void*)l, 16, 0, 0);
}

// ---------------------------------------------------------------- prep weights
__global__ __launch_bounds__(256) void prep_w(
    const float* __restrict__ g_w, const float* __restrict__ W_w,
    const float* __restrict__ W_b, const float* __restrict__ gamma,
    const float* __restrict__ beta, const float* __restrict__ mean,
    const float* __restrict__ var,
    unsigned short* __restrict__ gwb, unsigned short* __restrict__ wwb,
    float* __restrict__ bnA, float* __restrict__ bnB)
{
    int i = blockIdx.x * 256 + threadIdx.x;
    if (i < 256 * 512) { gwb[i] = f2bf(g_w[i]); wwb[i] = f2bf(W_w[i]); }
    if (i < 512) {
        float is = rsqrtf(var[i] + 1e-5f);
        float a = gamma[i] * is;
        bnA[i] = a;
        bnB[i] = (W_b[i] - mean[i]) * a + beta[i];
    }
}

// ---------------- fused Q+K build: read x once, write Q^T bf16 and pooled K^T bf16
// Block: 32 channels x 128 positions (= 2 image rows).  grid (32, 16, 8), block 256.
__global__ __launch_bounds__(256) void build_qk(
    const float* __restrict__ x, unsigned short* __restrict__ Qh,
    unsigned short* __restrict__ Kh)
{
    __shared__ float t[32][129];   // +1 pad: conflict-free transposed reads
    int b = blockIdx.z;
    int p0 = blockIdx.x * 128, c0 = blockIdx.y * 32;
    const float* xb = x + (long)b * 512 * 4096;
    int tid = threadIdx.x;
    for (int i = 0; i < 16; i++) {
        int idx = i * 256 + tid;
        int c = idx >> 7, p = idx & 127;
        t[c][p] = xb[(long)(c0 + c) * 4096 + p0 + p];
    }
    __syncthreads();
    unsigned short* qb = Qh + (long)b * 4096 * 512;
    for (int i = 0; i < 16; i++) {
        int idx = i * 256 + tid;
        int p = idx >> 5, c = idx & 31;
        qb[(long)(p0 + p) * 512 + c0 + c] = f2bf(t[c][p]);
    }
    unsigned short* kb = Kh + (long)b * 1024 * 512;
    int kp0 = p0 >> 2;   // pooled row (p0/128)*32
    for (int i = 0; i < 4; i++) {
        int idx = i * 256 + tid;
        int w = idx >> 5, c = idx & 31;
        float v = fmaxf(fmaxf(t[c][2 * w], t[c][2 * w + 1]),
                        fmaxf(t[c][64 + 2 * w], t[c][64 + 2 * w + 1]));
        kb[(long)(kp0 + w) * 512 + c0 + c] = f2bf(v);
    }
}

// ---------------- V build: Gp[ci][k'] = bf16(g_b[ci] + maxpool2(Gt)[ci][k'])
// Gt is bf16 [z][p=4096][ci=256] (base pre-offset).  grid (32, 32, G), block 256
__global__ __launch_bounds__(256) void build_v(
    const unsigned short* __restrict__ Gt, const float* __restrict__ g_b,
    unsigned short* __restrict__ Gp)
{
    int b = blockIdx.z;
    int k  = blockIdx.x * 32 + (threadIdx.x & 31);
    int ci = blockIdx.y * 8 + (threadIdx.x >> 5);
    int h = k >> 5, w = k & 31;
    const unsigned short* g = Gt + (long)b * 4096 * 256;
    long p = (long)(h * 128 + w * 2) * 256 + ci;
    float v0 = bf2f(g[p]),        v1 = bf2f(g[p + 256]);
    float v2 = bf2f(g[p + 64*256]), v3 = bf2f(g[p + 65*256]);
    float v = fmaxf(fmaxf(v0, v1), fmaxf(v2, v3)) + g_b[ci];
    Gp[(long)b * 256 * 1024 + (long)ci * 1024 + k] = f2bf(v);
}

// ---------------- streaming row max: one wave per 1024-elem row, coalesced.
__global__ __launch_bounds__(256) void smax_rows(
    const unsigned short* __restrict__ S, float* __restrict__ Smax)
{
    long row = (long)blockIdx.x * 4 + (threadIdx.x >> 6);
    int lane = threadIdx.x & 63;
    const unsigned short* r = S + row * 1024 + lane * 16;
    ushort8_t v0 = *(const ushort8_t*)r;
    ushort8_t v1 = *(const ushort8_t*)(r + 8);
    float m = -3.0e38f;
    for (int e = 0; e < 8; e++) m = fmaxf(m, fmaxf(bf2f(v0[e]), bf2f(v1[e])));
    for (int off = 32; off; off >>= 1) m = fmaxf(m, __shfl_xor(m, off));
    if (lane == 0) Smax[row] = m;
}

// ------------------------------------------- fused softmax + PV (deferred norm)
// Per block: 64 q-rows, full 1024 keys, 256 ci.  Row max from Smax (exact f32).
// S loads issued BEFORE gll16 so exp waits vmcnt(8), not vmcnt(0) (V DMA overlap).
__global__ __launch_bounds__(256) void pv_fused(
    const unsigned short* __restrict__ S, long sbstr,
    const float* __restrict__ Smax, long mxstr,
    const unsigned short* __restrict__ Gp, long gbstr,
    unsigned short* __restrict__ Y, long ybstr)
{
    __shared__ unsigned short lV[256 * 64];   // 32 KB
    __shared__ unsigned short lP[64 * 64];    // 8 KB
    __shared__ float li[64];

    const int tid = threadIdx.x;
    const int wid = tid >> 6, lane = tid & 63;

    // XCD-aware remap: each XCD owns one batch's q-blocks (S, V stay L2-local)
    unsigned gx = gridDim.x, gy = gridDim.y;
    unsigned nwg = gx * gy;
    unsigned lin = blockIdx.x + gx * blockIdx.y;
    unsigned l = ((nwg & 7u) == 0u) ? ((lin & 7u) * (nwg >> 3) + (lin >> 3)) : lin;
    unsigned bx = l % gx, by = l / gx;

    const int q0 = (int)bx * 64;
    const unsigned short* Sb = S + by * sbstr + (long)q0 * 1024;
    const unsigned short* Gb = Gp + by * gbstr;
    unsigned short* Yb = Y + by * ybstr + (long)q0 * 256;

    const int wr = wid >> 1, wc = wid & 1;
    const int lr = lane & 15, lg = lane >> 4;
    const int srA = lane >> 3;
    const int scg = (((lane & 7) ^ srA) << 3);
    const int pr = tid >> 2;            // lP row 0..63
    const int pc = (tid & 3) * 2;       // chunk base (2 chunks of 8 keys)

    const float m = Smax[by * mxstr + q0 + pr];   // exact row max (f32)

    f32x4 acc[2][8];
    for (int mi = 0; mi < 2; mi++)
        for (int ni = 0; ni < 8; ni++)
            acc[mi][ni] = (f32x4){0.f, 0.f, 0.f, 0.f};
    float psum = 0.f;                   // this thread's quarter-row sum of p

    for (int kb = 0; kb < 16; kb++) {
        __syncthreads();   // prev MFMA reads done
        // S chunk loads FIRST (oldest in vmcnt queue)
        const unsigned short* sp = Sb + (long)pr * 1024 + kb * 64 + pc * 8;
        ushort8_t v0 = *(const ushort8_t*)sp;
        ushort8_t v1 = *(const ushort8_t*)(sp + 8);
        // stage V tile [256 ci][64 keys] (linear LDS dest, pre-swizzled source)
        for (int i = 0; i < 8; i++) {
            int cibase = i * 32 + wid * 8;
            gll16(Gb + (long)(cibase + srA) * 1024 + kb * 64 + scg, &lV[cibase * 64]);
        }
        // exp from regs (waits only on S loads) -> lP; overlaps V DMA
        {
            ushort8_t o8;
            for (int e = 0; e < 8; e++) {
                float pe = __expf(bf2f(v0[e]) - m);
                psum += pe;
                o8[e] = f2bf(pe);
            }
            *(ushort8_t*)(&lP[pr * 64 + ((pc ^ (pr & 7)) * 8)]) = o8;
            for (int e = 0; e < 8; e++) {
                float pe = __expf(bf2f(v1[e]) - m);
                psum += pe;
                o8[e] = f2bf(pe);
            }
            *(ushort8_t*)(&lP[pr * 64 + (((pc + 1) ^ (pr & 7)) * 8)]) = o8;
        }
        __syncthreads();   // drains vmcnt(0) + LDS writes
        for (int ks = 0; ks < 2; ks++) {
            short8_t af[2], bfr[8];
            for (int mi = 0; mi < 2; mi++) {
                int row = wr * 32 + mi * 16 + lr;
                int ch = ((ks * 4 + lg) ^ (row & 7)) * 8;
                af[mi] = *(const short8_t*)(&lP[row * 64 + ch]);
            }
            for (int ni = 0; ni < 8; ni++) {
                int row = wc * 128 + ni * 16 + lr;
                int ch = ((ks * 4 + lg) ^ (row & 7)) * 8;
                bfr[ni] = *(const short8_t*)(&lV[row * 64 + ch]);
            }
            for (int mi = 0; mi < 2; mi++)
                for (int ni = 0; ni < 8; ni++)
                    acc[mi][ni] = __builtin_amdgcn_mfma_f32_16x16x32_bf16(
                        af[mi], bfr[ni], acc[mi][ni], 0, 0, 0);
        }
    }

    // reduce 4 partial sums per row -> li
    psum += __shfl_xor(psum, 1);
    psum += __shfl_xor(psum, 2);
    if ((tid & 3) == 0) li[pr] = 1.0f / psum;
    __syncthreads();

    // epilogue: Y[row][ci] = bf16(acc * 1/l)
    for (int mi = 0; mi < 2; mi++) {
        for (int ni = 0; ni < 8; ni++) {
            int ci = wc * 128 + ni * 16 + lr;
            int rbase = wr * 32 + mi * 16 + lg * 4;
            for (int r = 0; r < 4; r++) {
                int row = rbase + r;
                Yb[(long)row * 256 + ci] = f2bf(acc[mi][ni][r] * li[row]);
            }
        }
    }
}

// -------------------- fused QK^T + G-conv GEMM (shares A=Qh, K=512)
// grid (10, 32, G): bx<8 -> C=S tile (B=Kh_z);  bx>=8 -> C=Gt tile (B=gwb).
// 128x128 tile, BK=64, 4 waves 2x2; global_load_lds staging w/ XOR source swizzle.
__global__ __launch_bounds__(256) void gemm_qkg(
    const unsigned short* __restrict__ Qh,
    const unsigned short* __restrict__ Kh,
    const unsigned short* __restrict__ gwb,
    unsigned short* __restrict__ S,
    unsigned short* __restrict__ Gt)
{
    __shared__ unsigned short lA[128 * 64];
    __shared__ unsigned short lB[128 * 64];
    const int tid = threadIdx.x;
    const int wid = tid >> 6, lane = tid & 63;

    unsigned gx = gridDim.x, gy = gridDim.y;
    unsigned nwg = gx * gy * gridDim.z;
    unsigned lin = blockIdx.x + gx * (blockIdx.y + gy * blockIdx.z);
    unsigned l = ((nwg & 7u) == 0u) ? ((lin & 7u) * (nwg >> 3) + (lin >> 3)) : lin;
    unsigned bx = l % gx;
    unsigned rem = l / gx;
    unsigned by = rem % gy;
    unsigned bz = rem / gy;

    const int z = (int)bz;
    const int m0 = (int)by * 128;
    const unsigned short* Ab = Qh + (long)z * 4096 * 512;
    const unsigned short* Bb;
    unsigned short* Cb;
    int n0, ldc;
    if (bx < 8) {
        Bb = Kh + (long)z * 1024 * 512;  n0 = bx * 128;
        Cb = S + (long)z * 4096 * 1024;  ldc = 1024;
    } else {
        Bb = gwb;                         n0 = (bx - 8) * 128;
        Cb = Gt + (long)z * 4096 * 256;   ldc = 256;
    }

    const int wr = wid >> 1, wc = wid & 1;
    const int lr = lane & 15, lg = lane >> 4;
    const int srA = lane >> 3;
    const int scg = (((lane & 7) ^ srA) << 3);

    f32x4 acc[4][4];
    for (int mi = 0; mi < 4; mi++)
        for (int ni = 0; ni < 4; ni++)
            acc[mi][ni] = (f32x4){0.f, 0.f, 0.f, 0.f};

    for (int k0 = 0; k0 < 512; k0 += 64) {
        __syncthreads();
        for (int i = 0; i < 4; i++) {
            int rowbase = i * 32 + wid * 8;
            gll16(Ab + (long)(m0 + rowbase + srA) * 512 + k0 + scg, &lA[rowbase * 64]);
            gll16(Bb + (long)(n0 + rowbase + srA) * 512 + k0 + scg, &lB[rowbase * 64]);
        }
        __syncthreads();
        for (int kk = 0; kk < 2; kk++) {
            short8_t af[4], bfr[4];
            for (int mi = 0; mi < 4; mi++) {
                int row = wr * 64 + mi * 16 + lr;
                int ch = ((kk * 4 + lg) ^ (row & 7)) * 8;
                af[mi] = *(const short8_t*)(&lA[row * 64 + ch]);
            }
            for (int ni = 0; ni < 4; ni++) {
                int row = wc * 64 + ni * 16 + lr;
                int ch = ((kk * 4 + lg) ^ (row & 7)) * 8;
                bfr[ni] = *(const short8_t*)(&lB[row * 64 + ch]);
            }
            for (int mi = 0; mi < 4; mi++)
                for (int ni = 0; ni < 4; ni++)
                    acc[mi][ni] = __builtin_amdgcn_mfma_f32_16x16x32_bf16(
                        af[mi], bfr[ni], acc[mi][ni], 0, 0, 0);
        }
    }

    for (int mi = 0; mi < 4; mi++) {
        for (int ni = 0; ni < 4; ni++) {
            int ncol = n0 + wc * 64 + ni * 16 + lr;
            int mrow = m0 + wr * 64 + mi * 16 + lg * 4;
            for (int r = 0; r < 4; r++) {
                Cb[(long)(mrow + r) * ldc + ncol] = f2bf(acc[mi][ni][r]);
            }
        }
    }
}

// -------------------------------------------------------------------- GEMM
// C[m][n] = sum_k A[m][k]*B[n][k].  128x128 tile, BK=64, 4 waves 2x2.
// EPI: 0 f32 store, 1 bf16 store, 2 v*bnA[m]+bnB[m]+Xres f32 store.
template<int EPI>
__global__ __launch_bounds__(256) void gemm_abt(
    const unsigned short* __restrict__ A, int lda, long abstr,
    const unsigned short* __restrict__ B, int ldb, long bbstr,
    void* __restrict__ Cv, int ldc, long cbstr,
    int K,
    const float* __restrict__ bnA, const float* __restrict__ bnB,
    const float* __restrict__ Xres, long xbstr)
{
    __shared__ unsigned short lA[128 * 64];
    __shared__ unsigned short lB[128 * 64];
    const int tid = threadIdx.x;
    const int wid = tid >> 6, lane = tid & 63;

    unsigned gx = gridDim.x, gy = gridDim.y;
    unsigned nwg = gx * gy * gridDim.z;
    unsigned lin = blockIdx.x + gx * (blockIdx.y + gy * blockIdx.z);
    unsigned l = ((nwg & 7u) == 0u) ? ((lin & 7u) * (nwg >> 3) + (lin >> 3)) : lin;
    unsigned bx = l % gx;
    unsigned rem = l / gx;
    unsigned by = rem % gy;
    unsigned bz = rem / gy;

    const int z = (int)bz;
    const int m0 = (int)by * 128, n0 = (int)bx * 128;
    const unsigned short* Ab = A + z * abstr;
    const unsigned short* Bb = B + z * bbstr;
    const int wr = wid >> 1, wc = wid & 1;
    const int lr = lane & 15, lg = lane >> 4;

    const int srA = lane >> 3;                         // 0..7
    const int scg = (((lane & 7) ^ srA) << 3);         // element offset 0..56

    f32x4 acc[4][4];
    for (int mi = 0; mi < 4; mi++)
        for (int ni = 0; ni < 4; ni++)
            acc[mi][ni] = (f32x4){0.f, 0.f, 0.f, 0.f};

    for (int k0 = 0; k0 < K; k0 += 64) {
        __syncthreads();
        for (int i = 0; i < 4; i++) {
            int rowbase = i * 32 + wid * 8;
            gll16(Ab + (long)(m0 + rowbase + srA) * lda + k0 + scg, &lA[rowbase * 64]);
            gll16(Bb + (long)(n0 + rowbase + srA) * ldb + k0 + scg, &lB[rowbase * 64]);
        }
        __syncthreads();
        for (int kk = 0; kk < 2; kk++) {
            short8_t af[4], bfr[4];
            for (int mi = 0; mi < 4; mi++) {
                int row = wr * 64 + mi * 16 + lr;
                int ch = ((kk * 4 + lg) ^ (row & 7)) * 8;
                af[mi] = *(const short8_t*)(&lA[row * 64 + ch]);
            }
            for (int ni = 0; ni < 4; ni++) {
                int row = wc * 64 + ni * 16 + lr;
                int ch = ((kk * 4 + lg) ^ (row & 7)) * 8;
                bfr[ni] = *(const short8_t*)(&lB[row * 64 + ch]);
            }
            for (int mi = 0; mi < 4; mi++)
                for (int ni = 0; ni < 4; ni++)
                    acc[mi][ni] = __builtin_amdgcn_mfma_f32_16x16x32_bf16(
                        af[mi], bfr[ni], acc[mi][ni], 0, 0, 0);
        }
    }

    for (int mi = 0; mi < 4; mi++) {
        for (int ni = 0; ni < 4; ni++) {
            int ncol = n0 + wc * 64 + ni * 16 + lr;
            int mrow = m0 + wr * 64 + mi * 16 + lg * 4;
            for (int r = 0; r < 4; r++) {
                int row = mrow + r;
                float v = acc[mi][ni][r];
                long idx = z * cbstr + (long)row * ldc + ncol;
                if (EPI == 0) {
                    ((float*)Cv)[idx] = v;
                } else if (EPI == 1) {
                    ((unsigned short*)Cv)[idx] = f2bf(v);
                } else {
                    float o = v * bnA[row] + bnB[row] + Xres[z * xbstr + (long)row * ldc + ncol];
                    ((float*)Cv)[idx] = o;
                }
            }
        }
    }
}

// fallback if workspace too small (diagnostic: out = x)
__global__ void copy_residual(const float* __restrict__ x, float* __restrict__ out, long n)
{
    for (long i = blockIdx.x * 256ll + threadIdx.x; i < n; i += (long)gridDim.x * 256)
        out[i] = x[i];
}

extern "C" void kernel_launch(void* const* d_in, const int* in_sizes, int n_in,
                              void* d_out, int out_size, void* d_ws, size_t ws_size,
                              hipStream_t stream)
{
    const float* x     = (const float*)d_in[0];
    const float* g_w   = (const float*)d_in[1];
    const float* g_b   = (const float*)d_in[2];
    const float* W_w   = (const float*)d_in[3];
    const float* W_b   = (const float*)d_in[4];
    const float* gamma = (const float*)d_in[5];
    const float* beta  = (const float*)d_in[6];
    const float* mean  = (const float*)d_in[7];
    const float* var   = (const float*)d_in[8];
    float* out = (float*)d_out;

    char* ws = (char*)d_ws;
    size_t o = 0;
    auto alloc = [&](size_t bytes) { size_t r = o; o = (o + bytes + 255) & ~(size_t)255; return r; };
    size_t o_gwb = alloc(256 * 512 * 2);
    size_t o_wwb = alloc(512 * 256 * 2);
    size_t o_bnA = alloc(512 * 4);
    size_t o_bnB = alloc(512 * 4);
    size_t o_q   = alloc(8ull * 4096 * 512 * 2);   // Qh bf16
    size_t o_k   = alloc(8ull * 1024 * 512 * 2);   // Kh bf16
    size_t o_gp  = alloc(8ull * 256 * 1024 * 2);   // V^T (pooled g, bf16)
    size_t o_y   = alloc(8ull * 4096 * 256 * 2);   // Y (also holds Gt before pooling)
    size_t o_m   = alloc(8ull * 4096 * 4);         // Smax f32 (exact row max)
    size_t o_s   = o;                               // S bf16 logits
    const size_t srow_bytes = 1024ull * 2;          // one S row (bf16)
    const size_t sb1 = 4096ull * srow_bytes;        // one batch of S (8 MB)

    int G = 0, RC = 0;
    if      (o_s + 8 * sb1 <= ws_size) G = 8;
    else if (o_s + 4 * sb1 <= ws_size) G = 4;
    else if (o_s + 2 * sb1 <= ws_size) G = 2;
    else if (o_s + 1 * sb1 <= ws_size) G = 1;
    else {
        for (int rc = 2048; rc >= 128; rc >>= 1)
            if (o_s + (size_t)rc * srow_bytes <= ws_size) { RC = rc; break; }
        if (!RC) {
            copy_residual<<<dim3(2048), dim3(256), 0, stream>>>(x, out, (long)out_size);
            return;
        }
    }

    unsigned short* gwb = (unsigned short*)(ws + o_gwb);
    unsigned short* wwb = (unsigned short*)(ws + o_wwb);
    float* bnA = (float*)(ws + o_bnA);
    float* bnB = (float*)(ws + o_bnB);
    unsigned short* Qh  = (unsigned short*)(ws + o_q);
    unsigned short* Kh  = (unsigned short*)(ws + o_k);
    unsigned short* Gp  = (unsigned short*)(ws + o_gp);
    unsigned short* Y   = (unsigned short*)(ws + o_y);
    float* Smax         = (float*)(ws + o_m);
    unsigned short* S   = (unsigned short*)(ws + o_s);

    prep_w<<<dim3(512), dim3(256), 0, stream>>>(g_w, W_w, W_b, gamma, beta, mean, var,
                                                gwb, wwb, bnA, bnB);
    build_qk<<<dim3(32, 16, 8), dim3(256), 0, stream>>>(x, Qh, Kh);

    if (G) {
        for (int bg = 0; bg < 8; bg += G) {
            // fused QK^T + G-conv (shared A panels): S and Gt (into Y slot)
            gemm_qkg<<<dim3(10, 32, G), dim3(256), 0, stream>>>(
                Qh + (size_t)bg * 4096 * 512,
                Kh + (size_t)bg * 1024 * 512,
                gwb,
                S,
                Y + (size_t)bg * 4096 * 256);
            build_v<<<dim3(32, 32, G), dim3(256), 0, stream>>>(
                Y + (size_t)bg * 4096 * 256, g_b, Gp + (size_t)bg * 256 * 1024);
            smax_rows<<<dim3(G * 1024), dim3(256), 0, stream>>>(S, Smax);
            pv_fused<<<dim3(64, G), dim3(256), 0, stream>>>(
                S, 4096l * 1024,
                Smax, 4096,
                Gp + (size_t)bg * 256 * 1024, 256l * 1024,
                Y + (size_t)bg * 4096 * 256, 4096l * 256);
        }
    } else {
        // Row-chunked path (small workspace): separate G-conv first, then chunks.
        gemm_abt<1><<<dim3(2, 32, 8), dim3(256), 0, stream>>>(
            Qh, 512, 4096l * 512,
            gwb, 512, 0,
            (void*)Y, 256, 4096l * 256, 512,
            nullptr, nullptr, nullptr, 0);
        build_v<<<dim3(32, 32, 8), dim3(256), 0, stream>>>(Y, g_b, Gp);
        for (int b = 0; b < 8; b++) {
            for (int r0 = 0; r0 < 4096; r0 += RC) {
                const unsigned short* Aq = Qh + (size_t)b * 4096 * 512 + (size_t)r0 * 512;
                gemm_abt<1><<<dim3(8, RC / 128, 1), dim3(256), 0, stream>>>(
                    Aq, 512, 0,
                    Kh + (size_t)b * 1024 * 512, 512, 0,
                    (void*)S, 1024, 0, 512,
                    nullptr, nullptr, nullptr, 0);
                smax_rows<<<dim3(RC / 4), dim3(256), 0, stream>>>(S, Smax);
                pv_fused<<<dim3(RC / 64, 1), dim3(256), 0, stream>>>(
                    S, 0,
                    Smax, 0,
                    Gp + (size_t)b * 256 * 1024, 0,
                    Y + ((size_t)b * 4096 + r0) * 256, 0);
            }
        }
    }

    // W-conv + BN + residual: out[b][o][p] = (wwb·Y^T)*bnA[o]+bnB[o]+x  (M=512,N=4096,K=256)
    gemm_abt<2><<<dim3(32, 4, 8), dim3(256), 0, stream>>>(
        wwb, 256, 0,
        Y, 256, 4096l * 256,
        (void*)out, 4096, 512l * 4096, 256,
        bnA, bnB, x, 512l * 4096);
}

// Round 13
// 171.804 us; speedup vs baseline: 1.0774x; 1.0163x over previous
//
#include <hip/hip_runtime.h>
#include <stdint.h>

typedef __attribute__((ext_vector_type(4))) float f32x4;
typedef __attribute__((ext_vector_type(8))) short short8_t;     // 8 bf16 for MFMA operand
typedef __attribute__((ext_vector_type(8))) unsigned short ushort8_t;

__device__ __forceinline__ unsigned short f2bf(float f) {
    unsigned int u = __builtin_bit_cast(unsigned int, f);
    u = (u + 0x7fffu + ((u >> 16) & 1u)) >> 16;   // round-to-nearest-even
    return (unsigned short)u;
}
__device__ __forceinline__ float bf2f(unsigned short h) {
    unsigned int u = ((unsigned int)h) << 16;
    return __builtin_bit_cast(float, u);
}

// async global->LDS, 16B per lane. LDS dest = wave-uniform base + lane*16.
__device__ __forceinline__ void gll16(const unsigned short* g, unsigned short* l) {
    __builtin_amdgcn_global_load_lds(
        (const __attribute__((address_space(1))) void*)g,
        (__attribute__((address_space(3))) void*)l, 16, 0, 0);
}

// ---------------------------------------------------------------- prep weights
__global__ __launch_bounds__(256) void prep_w(
    const float* __restrict__ g_w, const float* __restrict__ W_w,
    const float* __restrict__ W_b, const float* __restrict__ gamma,
    const float* __restrict__ beta, const float* __restrict__ mean,
    const float* __restrict__ var,
    unsigned short* __restrict__ gwb, unsigned short* __restrict__ wwb,
    float* __restrict__ bnA, float* __restrict__ bnB)
{
    int i = blockIdx.x * 256 + threadIdx.x;
    if (i < 256 * 512) { gwb[i] = f2bf(g_w[i]); wwb[i] = f2bf(W_w[i]); }
    if (i < 512) {
        float is = rsqrtf(var[i] + 1e-5f);
        float a = gamma[i] * is;
        bnA[i] = a;
        bnB[i] = (W_b[i] - mean[i]) * a + beta[i];
    }
}

// ---------------- fused Q+K build: read x once (float4), write Q^T / pooled K^T
// as ushort8 (16B coalesced stores).  Block: 32 ch x 128 pos.  grid (32,16,8).
__global__ __launch_bounds__(256) void build_qk(
    const float* __restrict__ x, unsigned short* __restrict__ Qh,
    unsigned short* __restrict__ Kh)
{
    __shared__ float t[32][129];   // +1 pad; stride 129 ≡ 1 mod 32 (2-way max)
    int b = blockIdx.z;
    int p0 = blockIdx.x * 128, c0 = blockIdx.y * 32;
    const float* xb = x + (long)b * 512 * 4096;
    int tid = threadIdx.x;
    for (int i = 0; i < 4; i++) {
        int f4 = i * 256 + tid;            // 0..1023 float4s
        int c = f4 >> 5, p4 = (f4 & 31) * 4;
        float4 v = *(const float4*)(xb + (long)(c0 + c) * 4096 + p0 + p4);
        t[c][p4] = v.x; t[c][p4 + 1] = v.y; t[c][p4 + 2] = v.z; t[c][p4 + 3] = v.w;
    }
    __syncthreads();
    unsigned short* qb = Qh + (long)b * 4096 * 512;
    for (int i = 0; i < 2; i++) {
        int u = i * 256 + tid;             // 0..511
        int p = u >> 2, cg = (u & 3) * 8;
        ushort8_t o;
        for (int e = 0; e < 8; e++) o[e] = f2bf(t[cg + e][p]);
        *(ushort8_t*)(qb + (long)(p0 + p) * 512 + c0 + cg) = o;
    }
    unsigned short* kb = Kh + (long)b * 1024 * 512;
    int kp0 = p0 >> 2;   // pooled row base
    if (tid < 128) {
        int w = tid >> 2, cg = (tid & 3) * 8;
        ushort8_t o;
        for (int e = 0; e < 8; e++) {
            int c = cg + e;
            float v = fmaxf(fmaxf(t[c][2 * w], t[c][2 * w + 1]),
                            fmaxf(t[c][64 + 2 * w], t[c][64 + 2 * w + 1]));
            o[e] = f2bf(v);
        }
        *(ushort8_t*)(kb + (long)(kp0 + w) * 512 + c0 + cg) = o;
    }
}

// ---------------- V build: Gp[ci][k'] = bf16(g_b[ci] + maxpool2(Gt)[ci][k'])
__global__ __launch_bounds__(256) void build_v(
    const unsigned short* __restrict__ Gt, const float* __restrict__ g_b,
    unsigned short* __restrict__ Gp)
{
    int b = blockIdx.z;
    int k  = blockIdx.x * 32 + (threadIdx.x & 31);
    int ci = blockIdx.y * 8 + (threadIdx.x >> 5);
    int h = k >> 5, w = k & 31;
    const unsigned short* g = Gt + (long)b * 4096 * 256;
    long p = (long)(h * 128 + w * 2) * 256 + ci;
    float v0 = bf2f(g[p]),        v1 = bf2f(g[p + 256]);
    float v2 = bf2f(g[p + 64*256]), v3 = bf2f(g[p + 65*256]);
    float v = fmaxf(fmaxf(v0, v1), fmaxf(v2, v3)) + g_b[ci];
    Gp[(long)b * 256 * 1024 + (long)ci * 1024 + k] = f2bf(v);
}

// ------------------------------------------- fused scan + softmax + PV
// Per block: 64 q-rows, 1024 keys, 256 ci.
// Phase 0: wave-coalesced row-max scan (wave w -> rows w*16..+15, 32B/lane,
//          shfl reduce) -> lm; pulls S slice into L2 for the exp phase.
// Main: per 64-key block, S loads first (vmcnt overlap with V DMA), p=exp(s-m)
//       unnormalized -> bf16 -> MFMA; psum alongside; 1/l in epilogue.
__global__ __launch_bounds__(256) void pv_fused(
    const unsigned short* __restrict__ S, long sbstr,
    const unsigned short* __restrict__ Gp, long gbstr,
    unsigned short* __restrict__ Y, long ybstr)
{
    __shared__ unsigned short lV[256 * 64];   // 32 KB
    __shared__ unsigned short lP[64 * 64];    // 8 KB
    __shared__ float lm[64], li[64];

    const int tid = threadIdx.x;
    const int wid = tid >> 6, lane = tid & 63;

    // XCD-aware remap
    unsigned gx = gridDim.x, gy = gridDim.y;
    unsigned nwg = gx * gy;
    unsigned lin = blockIdx.x + gx * blockIdx.y;
    unsigned l = ((nwg & 7u) == 0u) ? ((lin & 7u) * (nwg >> 3) + (lin >> 3)) : lin;
    unsigned bx = l % gx, by = l / gx;

    const int q0 = (int)bx * 64;
    const unsigned short* Sb = S + by * sbstr + (long)q0 * 1024;
    const unsigned short* Gb = Gp + by * gbstr;
    unsigned short* Yb = Y + by * ybstr + (long)q0 * 256;

    // ---- phase 0: coalesced row-max scan (wave-parallel)
    for (int rr = 0; rr < 16; rr++) {
        int r = (wid << 4) + rr;
        const unsigned short* pS = Sb + (long)r * 1024 + lane * 16;
        ushort8_t v0 = *(const ushort8_t*)pS;
        ushort8_t v1 = *(const ushort8_t*)(pS + 8);
        float m = -3.0e38f;
        for (int e = 0; e < 8; e++)
            m = fmaxf(m, fmaxf(bf2f(v0[e]), bf2f(v1[e])));
        for (int off = 32; off; off >>= 1) m = fmaxf(m, __shfl_xor(m, off));
        if (lane == 0) lm[r] = m;
    }
    __syncthreads();

    const int wr = wid >> 1, wc = wid & 1;
    const int lr = lane & 15, lg = lane >> 4;
    const int srA = lane >> 3;
    const int scg = (((lane & 7) ^ srA) << 3);
    const int pr = tid >> 2;            // lP row 0..63
    const int pc = (tid & 3) * 2;       // chunk base (2 chunks of 8 keys)

    const float m = lm[pr];             // exact row max (f32)

    f32x4 acc[2][8];
    for (int mi = 0; mi < 2; mi++)
        for (int ni = 0; ni < 8; ni++)
            acc[mi][ni] = (f32x4){0.f, 0.f, 0.f, 0.f};
    float psum = 0.f;                   // this thread's quarter-row sum of p

    for (int kb = 0; kb < 16; kb++) {
        __syncthreads();   // prev MFMA reads done
        // S chunk loads FIRST (oldest in vmcnt queue; L2-hot after scan)
        const unsigned short* sp = Sb + (long)pr * 1024 + kb * 64 + pc * 8;
        ushort8_t v0 = *(const ushort8_t*)sp;
        ushort8_t v1 = *(const ushort8_t*)(sp + 8);
        // stage V tile [256 ci][64 keys] (linear LDS dest, pre-swizzled source)
        for (int i = 0; i < 8; i++) {
            int cibase = i * 32 + wid * 8;
            gll16(Gb + (long)(cibase + srA) * 1024 + kb * 64 + scg, &lV[cibase * 64]);
        }
        // exp from regs (waits only on S loads) -> lP; overlaps V DMA
        {
            ushort8_t o8;
            for (int e = 0; e < 8; e++) {
                float pe = __expf(bf2f(v0[e]) - m);
                psum += pe;
                o8[e] = f2bf(pe);
            }
            *(ushort8_t*)(&lP[pr * 64 + ((pc ^ (pr & 7)) * 8)]) = o8;
            for (int e = 0; e < 8; e++) {
                float pe = __expf(bf2f(v1[e]) - m);
                psum += pe;
                o8[e] = f2bf(pe);
            }
            *(ushort8_t*)(&lP[pr * 64 + (((pc + 1) ^ (pr & 7)) * 8)]) = o8;
        }
        __syncthreads();   // drains vmcnt(0) + LDS writes
        for (int ks = 0; ks < 2; ks++) {
            short8_t af[2], bfr[8];
            for (int mi = 0; mi < 2; mi++) {
                int row = wr * 32 + mi * 16 + lr;
                int ch = ((ks * 4 + lg) ^ (row & 7)) * 8;
                af[mi] = *(const short8_t*)(&lP[row * 64 + ch]);
            }
            for (int ni = 0; ni < 8; ni++) {
                int row = wc * 128 + ni * 16 + lr;
                int ch = ((ks * 4 + lg) ^ (row & 7)) * 8;
                bfr[ni] = *(const short8_t*)(&lV[row * 64 + ch]);
            }
            for (int mi = 0; mi < 2; mi++)
                for (int ni = 0; ni < 8; ni++)
                    acc[mi][ni] = __builtin_amdgcn_mfma_f32_16x16x32_bf16(
                        af[mi], bfr[ni], acc[mi][ni], 0, 0, 0);
        }
    }

    // reduce 4 partial sums per row -> li
    psum += __shfl_xor(psum, 1);
    psum += __shfl_xor(psum, 2);
    if ((tid & 3) == 0) li[pr] = 1.0f / psum;
    __syncthreads();

    // epilogue: Y[row][ci] = bf16(acc * 1/l)
    for (int mi = 0; mi < 2; mi++) {
        for (int ni = 0; ni < 8; ni++) {
            int ci = wc * 128 + ni * 16 + lr;
            int rbase = wr * 32 + mi * 16 + lg * 4;
            for (int r = 0; r < 4; r++) {
                int row = rbase + r;
                Yb[(long)row * 256 + ci] = f2bf(acc[mi][ni][r] * li[row]);
            }
        }
    }
}

// -------------------- fused QK^T + G-conv GEMM (shares A=Qh, K=512)
// grid (10, 32, G): bx<8 -> C=S tile (B=Kh_z);  bx>=8 -> C=Gt tile (B=gwb).
__global__ __launch_bounds__(256) void gemm_qkg(
    const unsigned short* __restrict__ Qh,
    const unsigned short* __restrict__ Kh,
    const unsigned short* __restrict__ gwb,
    unsigned short* __restrict__ S,
    unsigned short* __restrict__ Gt)
{
    __shared__ unsigned short lA[128 * 64];
    __shared__ unsigned short lB[128 * 64];
    const int tid = threadIdx.x;
    const int wid = tid >> 6, lane = tid & 63;

    unsigned gx = gridDim.x, gy = gridDim.y;
    unsigned nwg = gx * gy * gridDim.z;
    unsigned lin = blockIdx.x + gx * (blockIdx.y + gy * blockIdx.z);
    unsigned l = ((nwg & 7u) == 0u) ? ((lin & 7u) * (nwg >> 3) + (lin >> 3)) : lin;
    unsigned bx = l % gx;
    unsigned rem = l / gx;
    unsigned by = rem % gy;
    unsigned bz = rem / gy;

    const int z = (int)bz;
    const int m0 = (int)by * 128;
    const unsigned short* Ab = Qh + (long)z * 4096 * 512;
    const unsigned short* Bb;
    unsigned short* Cb;
    int n0, ldc;
    if (bx < 8) {
        Bb = Kh + (long)z * 1024 * 512;  n0 = bx * 128;
        Cb = S + (long)z * 4096 * 1024;  ldc = 1024;
    } else {
        Bb = gwb;                         n0 = (bx - 8) * 128;
        Cb = Gt + (long)z * 4096 * 256;   ldc = 256;
    }

    const int wr = wid >> 1, wc = wid & 1;
    const int lr = lane & 15, lg = lane >> 4;
    const int srA = lane >> 3;
    const int scg = (((lane & 7) ^ srA) << 3);

    f32x4 acc[4][4];
    for (int mi = 0; mi < 4; mi++)
        for (int ni = 0; ni < 4; ni++)
            acc[mi][ni] = (f32x4){0.f, 0.f, 0.f, 0.f};

    for (int k0 = 0; k0 < 512; k0 += 64) {
        __syncthreads();
        for (int i = 0; i < 4; i++) {
            int rowbase = i * 32 + wid * 8;
            gll16(Ab + (long)(m0 + rowbase + srA) * 512 + k0 + scg, &lA[rowbase * 64]);
            gll16(Bb + (long)(n0 + rowbase + srA) * 512 + k0 + scg, &lB[rowbase * 64]);
        }
        __syncthreads();
        for (int kk = 0; kk < 2; kk++) {
            short8_t af[4], bfr[4];
            for (int mi = 0; mi < 4; mi++) {
                int row = wr * 64 + mi * 16 + lr;
                int ch = ((kk * 4 + lg) ^ (row & 7)) * 8;
                af[mi] = *(const short8_t*)(&lA[row * 64 + ch]);
            }
            for (int ni = 0; ni < 4; ni++) {
                int row = wc * 64 + ni * 16 + lr;
                int ch = ((kk * 4 + lg) ^ (row & 7)) * 8;
                bfr[ni] = *(const short8_t*)(&lB[row * 64 + ch]);
            }
            for (int mi = 0; mi < 4; mi++)
                for (int ni = 0; ni < 4; ni++)
                    acc[mi][ni] = __builtin_amdgcn_mfma_f32_16x16x32_bf16(
                        af[mi], bfr[ni], acc[mi][ni], 0, 0, 0);
        }
    }

    for (int mi = 0; mi < 4; mi++) {
        for (int ni = 0; ni < 4; ni++) {
            int ncol = n0 + wc * 64 + ni * 16 + lr;
            int mrow = m0 + wr * 64 + mi * 16 + lg * 4;
            for (int r = 0; r < 4; r++) {
                Cb[(long)(mrow + r) * ldc + ncol] = f2bf(acc[mi][ni][r]);
            }
        }
    }
}

// -------------------------------------------------------------------- GEMM
// EPI: 0 f32 store, 1 bf16 store, 2 v*bnA[m]+bnB[m]+Xres f32 store.
template<int EPI>
__global__ __launch_bounds__(256) void gemm_abt(
    const unsigned short* __restrict__ A, int lda, long abstr,
    const unsigned short* __restrict__ B, int ldb, long bbstr,
    void* __restrict__ Cv, int ldc, long cbstr,
    int K,
    const float* __restrict__ bnA, const float* __restrict__ bnB,
    const float* __restrict__ Xres, long xbstr)
{
    __shared__ unsigned short lA[128 * 64];
    __shared__ unsigned short lB[128 * 64];
    const int tid = threadIdx.x;
    const int wid = tid >> 6, lane = tid & 63;

    unsigned gx = gridDim.x, gy = gridDim.y;
    unsigned nwg = gx * gy * gridDim.z;
    unsigned lin = blockIdx.x + gx * (blockIdx.y + gy * blockIdx.z);
    unsigned l = ((nwg & 7u) == 0u) ? ((lin & 7u) * (nwg >> 3) + (lin >> 3)) : lin;
    unsigned bx = l % gx;
    unsigned rem = l / gx;
    unsigned by = rem % gy;
    unsigned bz = rem / gy;

    const int z = (int)bz;
    const int m0 = (int)by * 128, n0 = (int)bx * 128;
    const unsigned short* Ab = A + z * abstr;
    const unsigned short* Bb = B + z * bbstr;
    const int wr = wid >> 1, wc = wid & 1;
    const int lr = lane & 15, lg = lane >> 4;

    const int srA = lane >> 3;
    const int scg = (((lane & 7) ^ srA) << 3);

    f32x4 acc[4][4];
    for (int mi = 0; mi < 4; mi++)
        for (int ni = 0; ni < 4; ni++)
            acc[mi][ni] = (f32x4){0.f, 0.f, 0.f, 0.f};

    for (int k0 = 0; k0 < K; k0 += 64) {
        __syncthreads();
        for (int i = 0; i < 4; i++) {
            int rowbase = i * 32 + wid * 8;
            gll16(Ab + (long)(m0 + rowbase + srA) * lda + k0 + scg, &lA[rowbase * 64]);
            gll16(Bb + (long)(n0 + rowbase + srA) * ldb + k0 + scg, &lB[rowbase * 64]);
        }
        __syncthreads();
        for (int kk = 0; kk < 2; kk++) {
            short8_t af[4], bfr[4];
            for (int mi = 0; mi < 4; mi++) {
                int row = wr * 64 + mi * 16 + lr;
                int ch = ((kk * 4 + lg) ^ (row & 7)) * 8;
                af[mi] = *(const short8_t*)(&lA[row * 64 + ch]);
            }
            for (int ni = 0; ni < 4; ni++) {
                int row = wc * 64 + ni * 16 + lr;
                int ch = ((kk * 4 + lg) ^ (row & 7)) * 8;
                bfr[ni] = *(const short8_t*)(&lB[row * 64 + ch]);
            }
            for (int mi = 0; mi < 4; mi++)
                for (int ni = 0; ni < 4; ni++)
                    acc[mi][ni] = __builtin_amdgcn_mfma_f32_16x16x32_bf16(
                        af[mi], bfr[ni], acc[mi][ni], 0, 0, 0);
        }
    }

    for (int mi = 0; mi < 4; mi++) {
        for (int ni = 0; ni < 4; ni++) {
            int ncol = n0 + wc * 64 + ni * 16 + lr;
            int mrow = m0 + wr * 64 + mi * 16 + lg * 4;
            for (int r = 0; r < 4; r++) {
                int row = mrow + r;
                float v = acc[mi][ni][r];
                long idx = z * cbstr + (long)row * ldc + ncol;
                if (EPI == 0) {
                    ((float*)Cv)[idx] = v;
                } else if (EPI == 1) {
                    ((unsigned short*)Cv)[idx] = f2bf(v);
                } else {
                    float o = v * bnA[row] + bnB[row] + Xres[z * xbstr + (long)row * ldc + ncol];
                    ((float*)Cv)[idx] = o;
                }
            }
        }
    }
}

// fallback if workspace too small (diagnostic: out = x)
__global__ void copy_residual(const float* __restrict__ x, float* __restrict__ out, long n)
{
    for (long i = blockIdx.x * 256ll + threadIdx.x; i < n; i += (long)gridDim.x * 256)
        out[i] = x[i];
}

extern "C" void kernel_launch(void* const* d_in, const int* in_sizes, int n_in,
                              void* d_out, int out_size, void* d_ws, size_t ws_size,
                              hipStream_t stream)
{
    const float* x     = (const float*)d_in[0];
    const float* g_w   = (const float*)d_in[1];
    const float* g_b   = (const float*)d_in[2];
    const float* W_w   = (const float*)d_in[3];
    const float* W_b   = (const float*)d_in[4];
    const float* gamma = (const float*)d_in[5];
    const float* beta  = (const float*)d_in[6];
    const float* mean  = (const float*)d_in[7];
    const float* var   = (const float*)d_in[8];
    float* out = (float*)d_out;

    char* ws = (char*)d_ws;
    size_t o = 0;
    auto alloc = [&](size_t bytes) { size_t r = o; o = (o + bytes + 255) & ~(size_t)255; return r; };
    size_t o_gwb = alloc(256 * 512 * 2);
    size_t o_wwb = alloc(512 * 256 * 2);
    size_t o_bnA = alloc(512 * 4);
    size_t o_bnB = alloc(512 * 4);
    size_t o_q   = alloc(8ull * 4096 * 512 * 2);   // Qh bf16
    size_t o_k   = alloc(8ull * 1024 * 512 * 2);   // Kh bf16
    size_t o_gp  = alloc(8ull * 256 * 1024 * 2);   // V^T (pooled g, bf16)
    size_t o_y   = alloc(8ull * 4096 * 256 * 2);   // Y (also holds Gt before pooling)
    size_t o_s   = o;                               // S bf16 logits
    const size_t srow_bytes = 1024ull * 2;          // one S row (bf16)
    const size_t sb1 = 4096ull * srow_bytes;        // one batch of S (8 MB)

    int G = 0, RC = 0;
    if      (o_s + 8 * sb1 <= ws_size) G = 8;
    else if (o_s + 4 * sb1 <= ws_size) G = 4;
    else if (o_s + 2 * sb1 <= ws_size) G = 2;
    else if (o_s + 1 * sb1 <= ws_size) G = 1;
    else {
        for (int rc = 2048; rc >= 128; rc >>= 1)
            if (o_s + (size_t)rc * srow_bytes <= ws_size) { RC = rc; break; }
        if (!RC) {
            copy_residual<<<dim3(2048), dim3(256), 0, stream>>>(x, out, (long)out_size);
            return;
        }
    }

    unsigned short* gwb = (unsigned short*)(ws + o_gwb);
    unsigned short* wwb = (unsigned short*)(ws + o_wwb);
    float* bnA = (float*)(ws + o_bnA);
    float* bnB = (float*)(ws + o_bnB);
    unsigned short* Qh  = (unsigned short*)(ws + o_q);
    unsigned short* Kh  = (unsigned short*)(ws + o_k);
    unsigned short* Gp  = (unsigned short*)(ws + o_gp);
    unsigned short* Y   = (unsigned short*)(ws + o_y);
    unsigned short* S   = (unsigned short*)(ws + o_s);

    prep_w<<<dim3(512), dim3(256), 0, stream>>>(g_w, W_w, W_b, gamma, beta, mean, var,
                                                gwb, wwb, bnA, bnB);
    build_qk<<<dim3(32, 16, 8), dim3(256), 0, stream>>>(x, Qh, Kh);

    if (G) {
        for (int bg = 0; bg < 8; bg += G) {
            // fused QK^T + G-conv (shared A panels): S and Gt (into Y slot)
            gemm_qkg<<<dim3(10, 32, G), dim3(256), 0, stream>>>(
                Qh + (size_t)bg * 4096 * 512,
                Kh + (size_t)bg * 1024 * 512,
                gwb,
                S,
                Y + (size_t)bg * 4096 * 256);
            build_v<<<dim3(32, 32, G), dim3(256), 0, stream>>>(
                Y + (size_t)bg * 4096 * 256, g_b, Gp + (size_t)bg * 256 * 1024);
            // fused scan + softmax + PV (deferred normalization)
            pv_fused<<<dim3(64, G), dim3(256), 0, stream>>>(
                S, 4096l * 1024,
                Gp + (size_t)bg * 256 * 1024, 256l * 1024,
                Y + (size_t)bg * 4096 * 256, 4096l * 256);
        }
    } else {
        // Row-chunked path (small workspace): separate G-conv first, then chunks.
        gemm_abt<1><<<dim3(2, 32, 8), dim3(256), 0, stream>>>(
            Qh, 512, 4096l * 512,
            gwb, 512, 0,
            (void*)Y, 256, 4096l * 256, 512,
            nullptr, nullptr, nullptr, 0);
        build_v<<<dim3(32, 32, 8), dim3(256), 0, stream>>>(Y, g_b, Gp);
        for (int b = 0; b < 8; b++) {
            for (int r0 = 0; r0 < 4096; r0 += RC) {
                const unsigned short* Aq = Qh + (size_t)b * 4096 * 512 + (size_t)r0 * 512;
                gemm_abt<1><<<dim3(8, RC / 128, 1), dim3(256), 0, stream>>>(
                    Aq, 512, 0,
                    Kh + (size_t)b * 1024 * 512, 512, 0,
                    (void*)S, 1024, 0, 512,
                    nullptr, nullptr, nullptr, 0);
                pv_fused<<<dim3(RC / 64, 1), dim3(256), 0, stream>>>(
                    S, 0,
                    Gp + (size_t)b * 256 * 1024, 0,
                    Y + ((size_t)b * 4096 + r0) * 256, 0);
            }
        }
    }

    // W-conv + BN + residual: out[b][o][p] = (wwb·Y^T)*bnA[o]+bnB[o]+x  (M=512,N=4096,K=256)
    gemm_abt<2><<<dim3(32, 4, 8), dim3(256), 0, stream>>>(
        wwb, 256, 0,
        Y, 256, 4096l * 256,
        (void*)out, 4096, 512l * 4096, 256,
        bnA, bnB, x, 512l * 4096);
}